// Round 5
// baseline (246.160 us; speedup 1.0000x reference)
//
#include <hip/hip_runtime.h>
#include <cstddef>
#include <cstdint>

#define H_    512
#define W_    512
#define NIMG  96           // 32 batch * 3 channels
#define PD_   16           // pad = KS/2
#define TY    64           // output rows per band
#define NROWS (TY + 31)    // 95 padded rows per band

// one DPP scan step: x += dpp_shifted(x); out-of-range lanes contribute 0
template <int CTRL, int RMASK>
__device__ __forceinline__ float dpp_add(float x) {
    int t = __builtin_amdgcn_update_dpp(0, __float_as_int(x), CTRL, RMASK, 0xf, true);
    return x + __int_as_float(t);
}

// wave64 inclusive prefix sum, pure VALU (6 dpp-adds)
__device__ __forceinline__ float wave_incl_scan(float x) {
    x = dpp_add<0x111, 0xf>(x);   // row_shr:1
    x = dpp_add<0x112, 0xf>(x);   // row_shr:2
    x = dpp_add<0x114, 0xf>(x);   // row_shr:4
    x = dpp_add<0x118, 0xf>(x);   // row_shr:8
    x = dpp_add<0x142, 0xa>(x);   // row_bcast:15 -> rows 1,3
    x = dpp_add<0x143, 0xc>(x);   // row_bcast:31 -> rows 2,3
    return x;
}

// TWO independent 32-lane inclusive scans (lanes 0-31 | 32-63), 5 dpp-adds.
// lo half scans tail-Sx, hi half scans tail-Sx^2 in ONE pass.
__device__ __forceinline__ float half_scan(float x) {
    x = dpp_add<0x111, 0xf>(x);
    x = dpp_add<0x112, 0xf>(x);
    x = dpp_add<0x114, 0xf>(x);
    x = dpp_add<0x118, 0xf>(x);
    x = dpp_add<0x142, 0xa>(x);   // row_bcast:15 within each 32-half only
    return x;
}

__device__ __forceinline__ float bcast63(float x) {
    return __int_as_float(__builtin_amdgcn_readlane(__float_as_int(x), 63));
}
__device__ __forceinline__ float bperm(int addr, float v) {
    return __int_as_float(__builtin_amdgcn_ds_bpermute(addr, __float_as_int(v)));
}

// HW packed f32->bf16 RNE convert (1 instr): lo16=bf16(a), hi16=bf16(b)
__device__ __forceinline__ uint32_t cvt_pk_bf16(float a, float b) {
    uint32_t r;
    asm("v_cvt_pk_bf16_f32 %0, %1, %2" : "=v"(r) : "v"(a), "v"(b));
    return r;
}

// Pending state carried across the 1-step software pipeline (ping-pong x2)
struct Pend {
    float dng, dnq;      // bperm S[lane+31] results (main g / q)
    float ubg, ubq;      // bperm tail-prefix results
    float s63g, s63q;    // lane-63 totals of the main scans
    float slog, sloq;    // exclusive-scan values S[lane-1]
    float xv;            // center x for this output row
};

// VERTICAL-FIRST localnorm, bf16 register history, EXPLICIT 1-step pipeline:
// front(k) = loads + rolling update + scans + bperm ISSUE;
// back(k-1) = combines + final math + store, consuming bperms issued a full
// step (~55 instrs) earlier -> lgkm latency fully covered by independent work.
// No LDS, no barriers; all cross-lane ops under full exec.
__global__ void __launch_bounds__(128)
localnorm_kernel(const float* __restrict__ xin, float* __restrict__ out)
{
    const int tid  = threadIdx.x;
    const int lane = tid & 63;
    const int wv   = tid >> 6;

    const int c0   = blockIdx.x * 128 + wv * 64;  // wave's first output col
    const int row0 = blockIdx.y * TY;
    const int img  = blockIdx.z;

    const float* __restrict__ src = xin + (size_t)img * (H_ * W_);
    float* __restrict__ dst = out + (size_t)img * (H_ * W_) + (size_t)row0 * W_ + c0 + lane;
    const float* __restrict__ xp = src + (size_t)row0 * W_ + c0 + lane;  // x reload base

    // padded col -> reflected original col (row-invariant)
    int pcm = c0 - PD_ + lane;                     // main: padded idx = lane
    const int ocm = (pcm < 0) ? -pcm : ((pcm > W_ - 1) ? 2 * (W_ - 1) - pcm : pcm);
    int pct = c0 - PD_ + 64 + (lane & 31);         // tail: both halves load same col
    const int oct = (pct > W_ - 1) ? 2 * (W_ - 1) - pct : pct;
    const bool lo32 = lane < 32;

    // precomputed ds_bpermute byte addresses
    const int A_dn  = ((lane + 31) & 63) << 2;     // S[lane+31]    (used lanes <= 32)
    const int A_u33 = ((lane - 33) & 63) << 2;     // tail-Sx  prefix (lanes >= 33)
    const int A_u1  = ((lane - 1)  & 63) << 2;     // tail-Sx2 prefix (lanes >= 33)

    auto rowbase = [&](int p) {
        int r = row0 + p - PD_;
        r = (r < 0) ? -r : ((r > H_ - 1) ? 2 * (H_ - 1) - r : r);
        return src + (size_t)r * W_;
    };

    // 4-deep prefetch ring for the new-row stream
    float gr[4], gtr[4];
#pragma unroll
    for (int p = 0; p < 4; ++p) {
        const float* rp = rowbase(p);
        gr[p]  = rp[ocm];
        gtr[p] = rp[oct];
    }

    // 32-deep packed bf16 history (static idx only) + vertical rolling sums
    uint32_t hist[32];
    float vmg = 0.f, vmq = 0.f, vt = 0.f;

    // prologue: padded rows 0..30 -> accumulate only, NO scans
#pragma unroll
    for (int p = 0; p < 31; ++p) {
        float g = gr[p & 3], gt = gtr[p & 3];
        {   const float* rp = rowbase(p + 4);      // max 34 < NROWS, no clamp
            gr[p & 3]  = rp[ocm];
            gtr[p & 3] = rp[oct];
        }
        uint32_t pk = cvt_pk_bf16(g, gt);          // lo16=bf16(g), hi16=bf16(gt)
        hist[p] = pk;
        float fg  = __uint_as_float(pk << 16);
        float fgt = __uint_as_float(pk & 0xffff0000u);
        vmg += fg;
        vmq += fg * fg;
        vt  += lo32 ? fgt : fgt * fgt;
    }
    hist[31] = 0u;                                 // step i=0 subtracts zero

    // x-center prefetch ring: rows 0..3
    float xr[4];
#pragma unroll
    for (int k = 0; k < 4; ++k) xr[k] = xp[(size_t)k * W_];

    Pend P[2];

    // front(k): everything up to and including the bperm issue
    auto front = [&](int k, Pend& Q) {
        // new padded row p = k+31 from ring; prefetch p+4
        float g = gr[(k + 3) & 3], gt = gtr[(k + 3) & 3];
        {   int pn = k + 35; if (pn > NROWS - 1) pn = NROWS - 1;
            const float* rp = rowbase(pn);
            gr[(k + 3) & 3]  = rp[ocm];
            gtr[(k + 3) & 3] = rp[oct];
        }
        // center x for this output row; prefetch row k+4
        Q.xv = xr[k & 3];
        {   int xn = k + 4; if (xn > TY - 1) xn = TY - 1;
            xr[k & 3] = xp[(size_t)xn * W_];
        }

        // bf16-pack, update rolling sums with exact cancellation
        uint32_t pk  = cvt_pk_bf16(g, gt);
        uint32_t old = hist[(k + 31) & 31];        // row k-1 leaves the window
        hist[(k + 31) & 31] = pk;
        float fg  = __uint_as_float(pk << 16);
        float fgt = __uint_as_float(pk & 0xffff0000u);
        float og  = __uint_as_float(old << 16);
        float ogt = __uint_as_float(old & 0xffff0000u);
        vmg += fg - og;
        vmq += fg * fg;
        vmq -= og * og;
        float dtl = fgt - ogt;
        float dth = fgt * fgt - ogt * ogt;
        vt += lo32 ? dtl : dth;

        // scans + bperm ISSUE (results consumed one step later)
        float sag = wave_incl_scan(vmg);
        float saq = wave_incl_scan(vmq);
        float sbt = half_scan(vt);
        Q.s63g = bcast63(sag);
        Q.s63q = bcast63(saq);
        Q.dng  = bperm(A_dn, sag);                 // S[lane+31], lanes <= 32
        Q.dnq  = bperm(A_dn, saq);
        Q.ubg  = bperm(A_u33, sbt);                // tail-Sx prefix, lanes >= 33
        Q.ubq  = bperm(A_u1,  sbt);                // tail-Sx2 prefix, lanes >= 33
        Q.slog = sag - vmg;                        // exclusive scan S[lane-1]
        Q.sloq = saq - vmq;
    };

    // back(j): combines + final math + store for output row j
    auto back = [&](int j, const Pend& Q) {
        float shig = (lane <= 32) ? Q.dng : (Q.s63g + Q.ubg);
        float shiq = (lane <= 32) ? Q.dnq : (Q.s63q + Q.ubq);
        float sg = shig - Q.slog;                  // 32x32 box sum of x
        float sq = shiq - Q.sloq;                  // 32x32 box sum of x^2
        float mg = sg * (1.f / 1024.f);
        float mq = sq * (1.f / 1024.f);
        float var = fabsf(mq - mg * mg);
        float r = (Q.xv - mg) * __builtin_amdgcn_rsqf(var + 1e-20f);
        r = fminf(fmaxf(r, -6.f), 6.f);
        dst[(size_t)j * W_] = r;
    };

    // pipelined main loop: output rows 0..63
    front(0, P[0]);
#pragma unroll
    for (int k = 1; k < TY; ++k) {
        front(k, P[k & 1]);          // issues row k's bperms
        back(k - 1, P[(k - 1) & 1]); // consumes row k-1's (long since landed)
    }
    back(TY - 1, P[(TY - 1) & 1]);
}

extern "C" void kernel_launch(void* const* d_in, const int* in_sizes, int n_in,
                              void* d_out, int out_size, void* d_ws, size_t ws_size,
                              hipStream_t stream) {
    (void)in_sizes; (void)n_in; (void)d_ws; (void)ws_size; (void)out_size;
    const float* x = (const float*)d_in[0];
    float* o = (float*)d_out;
    dim3 grid(W_ / 128, H_ / TY, NIMG);   // 4 x 8 x 96 = 3072 two-wave blocks, 12/CU
    localnorm_kernel<<<grid, dim3(128), 0, stream>>>(x, o);
}

// Round 6
// 204.667 us; speedup vs baseline: 1.2027x; 1.2027x over previous
//
#include <hip/hip_runtime.h>
#include <cstddef>
#include <cstdint>

#define H_    512
#define W_    512
#define NIMG  96           // 32 batch * 3 channels
#define PD_   16           // pad = KS/2
#define TY    128          // output rows per band
#define NROWS (TY + 31)    // 159 padded rows per band

// one DPP scan step: x += dpp_shifted(x); out-of-range lanes contribute 0
template <int CTRL, int RMASK>
__device__ __forceinline__ float dpp_add(float x) {
    int t = __builtin_amdgcn_update_dpp(0, __float_as_int(x), CTRL, RMASK, 0xf, true);
    return x + __int_as_float(t);
}

// wave64 inclusive prefix sum, pure VALU (6 dpp-adds, fused by GCNDPPCombine)
__device__ __forceinline__ float wave_incl_scan(float x) {
    x = dpp_add<0x111, 0xf>(x);   // row_shr:1
    x = dpp_add<0x112, 0xf>(x);   // row_shr:2
    x = dpp_add<0x114, 0xf>(x);   // row_shr:4
    x = dpp_add<0x118, 0xf>(x);   // row_shr:8
    x = dpp_add<0x142, 0xa>(x);   // row_bcast:15 -> rows 1,3
    x = dpp_add<0x143, 0xc>(x);   // row_bcast:31 -> rows 2,3
    return x;
}

__device__ __forceinline__ float bperm(int addr, float v) {
    return __int_as_float(__builtin_amdgcn_ds_bpermute(addr, __float_as_int(v)));
}

// 32-OUTPUT-COL WAVES: the 32-col output strip needs a 63-col padded window,
// which fits ONE 64-lane scan. Eliminates vs the 64-col variant: the tail
// load stream, the packed half-scan, 2 of 4 bperms, both readlanes, all lo32
// selects, and the bf16 history packing (hist is plain f32 -> exact math).
// Vertical-first rolling sums; 2 scans + 2 bperms per output row.
// No LDS, no barriers; all cross-lane ops under full exec mask.
__global__ void __launch_bounds__(128, 4)
localnorm_kernel(const float* __restrict__ xin, float* __restrict__ out)
{
    const int tid  = threadIdx.x;
    const int lane = tid & 63;
    const int wv   = tid >> 6;

    const int c0   = blockIdx.x * 64 + wv * 32;   // wave's first output col
    const int row0 = blockIdx.y * TY;
    const int img  = blockIdx.z;

    const float* __restrict__ src = xin + (size_t)img * (H_ * W_);
    float* __restrict__ dst = out + (size_t)img * (H_ * W_) + (size_t)row0 * W_ + c0 + (lane & 31);
    const float* __restrict__ xp = src + (size_t)row0 * W_ + c0 + (lane & 31); // x base (halves dup -> 1 txn)

    // padded col (lane l = padded idx l over cols c0-16 .. c0+47) -> reflected col
    int pcm = c0 - PD_ + lane;
    const int ocm = (pcm < 0) ? -pcm : ((pcm > W_ - 1) ? 2 * (W_ - 1) - pcm : pcm);

    // bperm byte address: S[lane+31] (used by lanes 0..31; others read garbage)
    const int A_dn = ((lane + 31) & 63) << 2;
    const bool emit = lane < 32;

    auto rowbase = [&](int p) {
        int r = row0 + p - PD_;
        r = (r < 0) ? -r : ((r > H_ - 1) ? 2 * (H_ - 1) - r : r);
        return src + (size_t)r * W_;
    };

    // 4-deep prefetch ring for the single row-load stream
    float gr[4];
#pragma unroll
    for (int p = 0; p < 4; ++p) gr[p] = rowbase(p)[ocm];

    // 32-deep f32 history of g (static idx only) + vertical rolling sums
    float hist[32];
    float vmg = 0.f, vmq = 0.f;

    // prologue: padded rows 0..30 -> accumulate only, NO scans
#pragma unroll
    for (int p = 0; p < 31; ++p) {
        float g = gr[p & 3];
        gr[p & 3] = rowbase(p + 4)[ocm];           // p+4 <= 34 < NROWS
        hist[p] = g;
        vmg += g;
        vmq = fmaf(g, g, vmq);
    }
    hist[31] = 0.f;                                // step i=0 subtracts zero

    // x-center prefetch ring: rows 0..3
    float xr[4];
#pragma unroll
    for (int k = 0; k < 4; ++k) xr[k] = xp[(size_t)k * W_];

    // main: output rows 0..TY-1 in four 32-step blocks (all slots static in j)
    for (int pb = 0; pb < 4; ++pb) {
        const int ib = pb * 32;
#pragma unroll
        for (int j = 0; j < 32; ++j) {
            const int i = ib + j;                  // output row (uniform)
            // new padded row p = i+31 from ring; prefetch p+4
            float g = gr[(j + 3) & 3];
            {   int pn = i + 35; if (pn > NROWS - 1) pn = NROWS - 1;
                gr[(j + 3) & 3] = rowbase(pn)[ocm];
            }
            // center x for this output row; prefetch row i+4
            float xv = xr[j & 3];
            {   int xn = i + 4; if (xn > TY - 1) xn = TY - 1;
                xr[j & 3] = xp[(size_t)xn * W_];
            }

            // rolling vertical window: add row i+31, drop row i-1 (exact f32)
            float og = hist[(j + 31) & 31];
            hist[(j + 31) & 31] = g;
            vmg += g - og;
            vmq = fmaf(g, g, vmq);
            vmq = fmaf(og, -og, vmq);

            // horizontal 32-box over the 63-col window: box = S[l+31] - S[l-1]
            float sag = wave_incl_scan(vmg);
            float saq = wave_incl_scan(vmq);
            float dng = bperm(A_dn, sag);          // S[lane+31]
            float dnq = bperm(A_dn, saq);
            float sg = dng - (sag - vmg);          // 32x32 box sum of x
            float sq = dnq - (saq - vmq);          // 32x32 box sum of x^2

            // scaled epilogue: (xv - mg)/sqrt(var) == (1024 xv - sg)/sqrt(1024 sq - sg^2)
            float t  = fmaf(sq, 1024.f, 1e-12f);
            float vs = fmaf(sg, -sg, t);           // 1024^2 * var + eps
            float num = fmaf(xv, 1024.f, -sg);     // 1024 * (xv - mg)
            float r = num * __builtin_amdgcn_rsqf(vs);
            r = fminf(fmaxf(r, -6.f), 6.f);
            if (emit) dst[(size_t)i * W_] = r;     // lanes 0..31 carry the outputs
        }
    }
}

extern "C" void kernel_launch(void* const* d_in, const int* in_sizes, int n_in,
                              void* d_out, int out_size, void* d_ws, size_t ws_size,
                              hipStream_t stream) {
    (void)in_sizes; (void)n_in; (void)d_ws; (void)ws_size; (void)out_size;
    const float* x = (const float*)d_in[0];
    float* o = (float*)d_out;
    dim3 grid(W_ / 64, H_ / TY, NIMG);    // 8 x 4 x 96 = 3072 two-wave blocks, 12/CU
    localnorm_kernel<<<grid, dim3(128), 0, stream>>>(x, o);
}

// Round 8
// 202.605 us; speedup vs baseline: 1.2150x; 1.0102x over previous
//
#include <hip/hip_runtime.h>
#include <cstddef>
#include <cstdint>

#define H_    512
#define W_    512
#define NIMG  96           // 32 batch * 3 channels
#define PD_   16           // pad = KS/2
#define TY    128          // output rows per band
#define NROWS (TY + 31)    // 159 padded rows per band

// one DPP scan step: x += dpp_shifted(x); out-of-range lanes contribute 0
template <int CTRL, int RMASK>
__device__ __forceinline__ float dpp_add(float x) {
    int t = __builtin_amdgcn_update_dpp(0, __float_as_int(x), CTRL, RMASK, 0xf, true);
    return x + __int_as_float(t);
}

// wave64 inclusive prefix sum, pure VALU (6 dpp-adds, fused by GCNDPPCombine)
__device__ __forceinline__ float wave_incl_scan(float x) {
    x = dpp_add<0x111, 0xf>(x);   // row_shr:1
    x = dpp_add<0x112, 0xf>(x);   // row_shr:2
    x = dpp_add<0x114, 0xf>(x);   // row_shr:4
    x = dpp_add<0x118, 0xf>(x);   // row_shr:8
    x = dpp_add<0x142, 0xa>(x);   // row_bcast:15 -> rows 1,3
    x = dpp_add<0x143, 0xc>(x);   // row_bcast:31 -> rows 2,3
    return x;
}

__device__ __forceinline__ float bperm(int addr, float v) {
    return __int_as_float(__builtin_amdgcn_ds_bpermute(addr, __float_as_int(v)));
}

// 32-OUTPUT-COL WAVES (r6 structure, ds_bpermute restored = known-good math),
// TWO OUTPUT ROWS PER UNROLLED BODY: both vertical updates first, then 4
// independent scan chains (ILP=4 on the DPP pipe), then all 4 bpermutes
// issued together (one lgkm drain), then 2 epilogues. Same persistent state
// as r6 (hist/rings, all static indices) -> no scratch risk.
// No LDS allocation, no barriers; all cross-lane ops under full exec mask.
__global__ void __launch_bounds__(128, 4)
localnorm_kernel(const float* __restrict__ xin, float* __restrict__ out)
{
    const int tid  = threadIdx.x;
    const int lane = tid & 63;
    const int wv   = tid >> 6;

    const int c0   = blockIdx.x * 64 + wv * 32;   // wave's first output col
    const int row0 = blockIdx.y * TY;
    const int img  = blockIdx.z;

    const float* __restrict__ src = xin + (size_t)img * (H_ * W_);
    float* __restrict__ dst = out + (size_t)img * (H_ * W_) + (size_t)row0 * W_ + c0 + (lane & 31);
    const float* __restrict__ xp = src + (size_t)row0 * W_ + c0 + (lane & 31); // x base (halves dup -> 1 txn)

    // padded col (lane l = padded idx l over cols c0-16 .. c0+47) -> reflected col
    int pcm = c0 - PD_ + lane;
    const int ocm = (pcm < 0) ? -pcm : ((pcm > W_ - 1) ? 2 * (W_ - 1) - pcm : pcm);

    // bperm byte address: S[lane+31] (used by lanes 0..31; others read garbage)
    const int A_dn = ((lane + 31) & 63) << 2;
    const bool emit = lane < 32;

    auto rowbase = [&](int p) {
        int r = row0 + p - PD_;
        r = (r < 0) ? -r : ((r > H_ - 1) ? 2 * (H_ - 1) - r : r);
        return src + (size_t)r * W_;
    };

    // 4-deep prefetch ring for the single row-load stream
    float gr[4];
#pragma unroll
    for (int p = 0; p < 4; ++p) gr[p] = rowbase(p)[ocm];

    // 32-deep f32 history of g (static idx only) + vertical rolling sums
    float hist[32];
    float vmg = 0.f, vmq = 0.f;

    // prologue: padded rows 0..30 -> accumulate only, NO scans
#pragma unroll
    for (int p = 0; p < 31; ++p) {
        float g = gr[p & 3];
        gr[p & 3] = rowbase(p + 4)[ocm];           // p+4 <= 34 < NROWS
        hist[p] = g;
        vmg += g;
        vmq = fmaf(g, g, vmq);
    }
    hist[31] = 0.f;                                // step i=0 subtracts zero

    // x-center prefetch ring: rows 0..3
    float xr[4];
#pragma unroll
    for (int k = 0; k < 4; ++k) xr[k] = xp[(size_t)k * W_];

    // main: output rows 0..TY-1, four 32-row blocks, TWO rows per body
    for (int pb = 0; pb < 4; ++pb) {
        const int ib = pb * 32;
#pragma unroll
        for (int j = 0; j < 32; j += 2) {
            const int iA = ib + j;                 // even output row (uniform)
            const int iB = iA + 1;                 // odd  output row

            // --- loads for both rows (issued first, consumed 2 pairs later)
            float gA = gr[(j + 3) & 3];
            {   int pn = iA + 35; if (pn > NROWS - 1) pn = NROWS - 1;
                gr[(j + 3) & 3] = rowbase(pn)[ocm];
            }
            float gB = gr[(j + 4) & 3];
            {   int pn = iB + 35; if (pn > NROWS - 1) pn = NROWS - 1;
                gr[(j + 4) & 3] = rowbase(pn)[ocm];
            }
            float xvA = xr[j & 3];
            {   int xn = iA + 4; if (xn > TY - 1) xn = TY - 1;
                xr[j & 3] = xp[(size_t)xn * W_];
            }
            float xvB = xr[(j + 1) & 3];
            {   int xn = iB + 4; if (xn > TY - 1) xn = TY - 1;
                xr[(j + 1) & 3] = xp[(size_t)xn * W_];
            }

            // --- both vertical rolling updates (serial but cheap, exact f32)
            float ogA = hist[(j + 31) & 31];       // padded row iA-1
            hist[(j + 31) & 31] = gA;              // padded row iA+31
            float ogB = hist[j];                   // ((j+1)+31)&31 == j
            hist[j] = gB;
            float vmgA = vmg + (gA - ogA);
            float vmqA = fmaf(gA, gA, vmq);
            vmqA = fmaf(ogA, -ogA, vmqA);
            float vmgB = vmgA + (gB - ogB);
            float vmqB = fmaf(gB, gB, vmqA);
            vmqB = fmaf(ogB, -ogB, vmqB);
            vmg = vmgB; vmq = vmqB;

            // --- 4 independent scan chains (ILP=4 on the DPP pipe)
            float sagA = wave_incl_scan(vmgA);
            float saqA = wave_incl_scan(vmqA);
            float sagB = wave_incl_scan(vmgB);
            float saqB = wave_incl_scan(vmqB);

            // --- all 4 bpermutes issued together; one lgkm drain covers all
            float dngA = bperm(A_dn, sagA);        // S[lane+31]
            float dnqA = bperm(A_dn, saqA);
            float dngB = bperm(A_dn, sagB);
            float dnqB = bperm(A_dn, saqB);

            // --- combines + epilogues (box = S[l+31] - S[l-1])
            float sgA = dngA - (sagA - vmgA);      // 32x32 box sum of x
            float sqA = dnqA - (saqA - vmqA);      // 32x32 box sum of x^2
            float sgB = dngB - (sagB - vmgB);
            float sqB = dnqB - (saqB - vmqB);

            // scaled: (xv-mg)/sqrt(var) == (1024 xv - sg)/sqrt(1024 sq - sg^2)
            float tA  = fmaf(sqA, 1024.f, 1e-12f);
            float vsA = fmaf(sgA, -sgA, tA);
            float nA  = fmaf(xvA, 1024.f, -sgA);
            float rA  = nA * __builtin_amdgcn_rsqf(vsA);
            rA = fminf(fmaxf(rA, -6.f), 6.f);

            float tB  = fmaf(sqB, 1024.f, 1e-12f);
            float vsB = fmaf(sgB, -sgB, tB);
            float nB  = fmaf(xvB, 1024.f, -sgB);
            float rB  = nB * __builtin_amdgcn_rsqf(vsB);
            rB = fminf(fmaxf(rB, -6.f), 6.f);

            if (emit) {
                dst[(size_t)iA * W_] = rA;         // lanes 0..31 carry outputs
                dst[(size_t)iB * W_] = rB;
            }
        }
    }
}

extern "C" void kernel_launch(void* const* d_in, const int* in_sizes, int n_in,
                              void* d_out, int out_size, void* d_ws, size_t ws_size,
                              hipStream_t stream) {
    (void)in_sizes; (void)n_in; (void)d_ws; (void)ws_size; (void)out_size;
    const float* x = (const float*)d_in[0];
    float* o = (float*)d_out;
    dim3 grid(W_ / 64, H_ / TY, NIMG);    // 8 x 4 x 96 = 3072 two-wave blocks, 12/CU
    localnorm_kernel<<<grid, dim3(128), 0, stream>>>(x, o);
}